// Round 4
// baseline (389.470 us; speedup 1.0000x reference)
//
#include <hip/hip_runtime.h>
#include <stdint.h>
#include <stddef.h>

#define LN_EPS 1e-5f

typedef __bf16 bf16;
typedef __bf16 bf16x8 __attribute__((ext_vector_type(8)));
typedef __bf16 bf16x4 __attribute__((ext_vector_type(4)));
typedef float f32x4 __attribute__((ext_vector_type(4)));

// async global->LDS, 16B per lane. LDS dest must be wave-uniform base + lane*16.
#define GL16(gp, lp)                                                                   \
  __builtin_amdgcn_global_load_lds((__attribute__((address_space(1))) uint32_t*)(gp),  \
                                   (__attribute__((address_space(3))) uint32_t*)(lp),  \
                                   16, 0, 0)

#define SBAR   asm volatile("s_barrier" ::: "memory")
#define VMW(N) asm volatile("s_waitcnt vmcnt(" #N ")" ::: "memory")
#define LGK(N) asm volatile("s_waitcnt lgkmcnt(" #N ")" ::: "memory")
#define NOWAIT ((void)0)

// ---------------------------------------------------------------------------
// single fp32 -> bf16 convert kernel for all three tensors (one launch)
// ---------------------------------------------------------------------------
#define XV4   6291456           // x:      25,165,824 f32 / 4
#define WQV4  442368            // w_qkv:   1,769,472 f32 / 4
#define WPV4  147456            // w_proj:    589,824 f32 / 4
__global__ __launch_bounds__(256) void cvt_all(const float* __restrict__ x,
                                               const float* __restrict__ wq,
                                               const float* __restrict__ wp,
                                               bf16* __restrict__ xb,
                                               bf16* __restrict__ wqb,
                                               bf16* __restrict__ wpb) {
  int i = blockIdx.x * 256 + threadIdx.x;
  const float* src; bf16* dst; int off;
  if (i < XV4)              { src = x;  dst = xb;  off = i; }
  else if (i < XV4 + WQV4)  { src = wq; dst = wqb; off = i - XV4; }
  else                      { src = wp; dst = wpb; off = i - (XV4 + WQV4); }
  const float4 v = ((const float4*)src)[off];
  bf16x4 o;
  o[0] = (bf16)v.x; o[1] = (bf16)v.y; o[2] = (bf16)v.z; o[3] = (bf16)v.w;
  ((bf16x4*)dst)[off] = o;
}

// ---------------------------------------------------------------------------
// 256x256-tile, 8-wave (2Mx4N), wave-split-staged pipelined GEMM core, K=768.
// K-halves kh = 0..23 (32 wide). Unit = 256x32 bf16 = 16 KB.
//
// The r2 kernel was fetch-LATENCY-bound (87 us invariant under two different
// schedules; per-CU in-flight 48 KB < latency*demand). Fix:
//  * Waves 0-3 stage ONLY A (6 slots, 96 KB; stage A(kh+5) at even(kh); in
//    flight 4-5 units = 64-80 KB; issued 10 phases before use -> covers HBM).
//  * Waves 4-7 stage ONLY B (3 slots, 48 KB; stage B(kh+2) at odd(kh); B is
//    L2-hot w_qkv, 2-phase cover suffices). Separate per-group vmcnt ledgers:
//    the shallow B stream no longer forces drains of the deep A stream.
//  Per unit: 4 GL16 per thread of the 4-wave group (16 rows per GL16).
//  LDS layout identical to r2 (row-major 256x32/unit, source chunk swizzle
//  chunk ^= (row>>1)&3, read col colE) -> conflict-free ds_read_b128.
//
// A-wave vmcnt ledger (4 GL16/unit): prologue A0..A4 (20) VMW(16)->A0.
//  even(kh) kh<=18: stage A(kh+5); outstanding A(kh+1..kh+5)=20; VMW(16)
//  completes A(kh+1) (needed by odd(kh) pair-prefetch). Tail: VMW(12/8/4/0).
// B-wave ledger: prologue B0,B1 (8) VMW(4)->B0. odd(kh) kh<=21: stage
//  B(kh+2). even-phase end: outstanding = B(kh+1) only -> VMW(0) (L2-hot).
// ds ledger (all waves): even: +4 af1, LGK(4) completes the 8 pair reads;
//  odd: +8 pair(kh+1), LGK(8) completes the 4 af1.
// ---------------------------------------------------------------------------
#define STG(KH, SL) do {                                         \
    GL16(g0 + (size_t)(KH) * 32, myLds + (SL) * 8192);           \
    GL16(g1 + (size_t)(KH) * 32, myLds + (SL) * 8192 + 512);     \
    GL16(g2 + (size_t)(KH) * 32, myLds + (SL) * 8192 + 1024);    \
    GL16(g3 + (size_t)(KH) * 32, myLds + (SL) * 8192 + 1536);    \
  } while (0)

#define RD_B(DST, SL)                                                              \
    _Pragma("unroll") for (int n = 0; n < 4; ++n)                                  \
      DST[n] = *(const bf16x8*)(ldsB + (SL) * 8192 + (rB + n * 16) * 32 + colE)

#define RD_A0(DST, SL)                                                             \
    _Pragma("unroll") for (int m = 0; m < 4; ++m)                                  \
      DST[m] = *(const bf16x8*)(ldsA + (SL) * 8192 + (rA + m * 16) * 32 + colE)

#define RD_A1(SL)                                                                  \
    _Pragma("unroll") for (int m = 0; m < 4; ++m)                                  \
      af1[m] = *(const bf16x8*)(ldsA + (SL) * 8192 + (rA + 64 + m * 16) * 32 + colE)

#define MM(AF, BF, MO)                                                             \
    _Pragma("unroll") for (int m = 0; m < 4; ++m)                                  \
      _Pragma("unroll") for (int n = 0; n < 4; ++n)                                \
        acc[(MO) + m][n] = __builtin_amdgcn_mfma_f32_16x16x32_bf16(                \
            AF[m], BF[n], acc[(MO) + m][n], 0, 0, 0)

#define EVP(KH, A0C, BFC, STGA, WA, WB) do {          \
    RD_A1((KH) % 6);                                  \
    if ((STGA) && isA) STG((KH) + 5, ((KH) + 5) % 6); \
    LGK(4);                                           \
    __builtin_amdgcn_sched_barrier(0);                \
    __builtin_amdgcn_s_setprio(1);                    \
    MM(A0C, BFC, 0);                                  \
    __builtin_amdgcn_s_setprio(0);                    \
    if (isA) { WA; } else { WB; }                     \
    SBAR;                                             \
  } while (0)

#define ODP(KH, A0N, BFN, BFC, STGB) do {             \
    RD_B(BFN, ((KH) + 1) % 3);                        \
    RD_A0(A0N, ((KH) + 1) % 6);                       \
    if ((STGB) && !isA) STG((KH) + 2, ((KH) + 2) % 3);\
    LGK(8);                                           \
    __builtin_amdgcn_sched_barrier(0);                \
    __builtin_amdgcn_s_setprio(1);                    \
    MM(af1, BFC, 4);                                  \
    __builtin_amdgcn_s_setprio(0);                    \
    SBAR;                                             \
  } while (0)

#define KHPAIR(KA, KB)                                            \
  EVP(KA, af0X, bfX, 1, VMW(16), VMW(0)); ODP(KA, af0Y, bfY, bfX, 1); \
  EVP(KB, af0Y, bfY, 1, VMW(16), VMW(0)); ODP(KB, af0X, bfX, bfY, 1);

__device__ __forceinline__ void gemm256(const bf16* gsrc, bf16* sh, f32x4 acc[8][4]) {
  const int tid  = threadIdx.x;
  const int lane = tid & 63;
  const int wave = tid >> 6;
  const bool isA = wave < 4;
  const int grp_w = wave & 3;
  const int l16  = lane & 15;
  // read column (elems), swizzled to match source pre-swizzle
  const int colE = ((((lane >> 4) * 16) ^ (((l16 >> 1) & 3) << 4)) >> 1);
  bf16* const ldsA  = sh;                    // 6 slots x 8192 elems (96 KB)
  bf16* const ldsB  = sh + 49152;            // 3 slots x 8192 elems (48 KB)
  bf16* const myLds = (isA ? ldsA : ldsB) + grp_w * 2048 + lane * 8;
  const bf16* g0 = gsrc;                     // instruction i covers rows +i*16
  const bf16* g1 = gsrc + 12288;
  const bf16* g2 = gsrc + 24576;
  const bf16* g3 = gsrc + 36864;
  const int wm = wave >> 2, wn = wave & 3;
  const int rA = wm * 128 + l16;             // + 64*mh + m*16
  const int rB = wn * 64 + l16;              // + n*16
  bf16x8 af0X[4], af0Y[4], af1[4], bfX[4], bfY[4];

  // prologue: A-waves stage A0..A4 (5 units), B-waves B0,B1 (2 units)
  if (isA) {
    STG(0, 0); STG(1, 1); STG(2, 2); STG(3, 3); STG(4, 4);
    VMW(16);                                 // A0 resident
  } else {
    STG(0, 0); STG(1, 1);
    VMW(4);                                  // B0 resident
  }
  SBAR;
  RD_B(bfX, 0);                              // pair-0 prefetch ("phase -1")
  RD_A0(af0X, 0);

  KHPAIR(0, 1)  KHPAIR(2, 3)  KHPAIR(4, 5)  KHPAIR(6, 7)  KHPAIR(8, 9)
  KHPAIR(10, 11)  KHPAIR(12, 13)  KHPAIR(14, 15)  KHPAIR(16, 17)

  EVP(18, af0X, bfX, 1, VMW(16), VMW(0)); ODP(18, af0Y, bfY, bfX, 1);  // A23 staged
  EVP(19, af0Y, bfY, 0, VMW(12), VMW(0)); ODP(19, af0X, bfX, bfY, 1);
  EVP(20, af0X, bfX, 0, VMW(8),  VMW(0)); ODP(20, af0Y, bfY, bfX, 1);
  EVP(21, af0Y, bfY, 0, VMW(4),  VMW(0)); ODP(21, af0X, bfX, bfY, 1);  // B23 staged
  EVP(22, af0X, bfX, 0, VMW(0),  VMW(0)); ODP(22, af0Y, bfY, bfX, 0);
  EVP(23, af0Y, bfY, 0, NOWAIT, NOWAIT);
  // final odd (kh=23): only af1's 4 reads outstanding
  LGK(0);
  __builtin_amdgcn_sched_barrier(0);
  __builtin_amdgcn_s_setprio(1);
  MM(af1, bfY, 4);
  __builtin_amdgcn_s_setprio(0);
  asm volatile("s_waitcnt vmcnt(0) lgkmcnt(0)" ::: "memory");
  __syncthreads();
}

// ---------------------------------------------------------------------------
// Pass 1: k/v GEMM + fused p2-weighted k*v reduction. Grid (6, 128) = 768.
// XCD clustering: the 6 hh-blocks sharing an A mblk-tile are CONSECUTIVE on
// ONE XCD (xcd = lin&7 round-robin; mblk = xcd + 8*(j/6), hh = j%6) -> A is
// fetched once per XCD L2 and re-read 5x from L2 (was: 6 XCDs via L3).
// Epilogue: transposed bf16 spill shT[c][n] stride 264 with 8-elem-block XOR
// permute (blk ^= (c ^ (c>>3))&7) -> conflict-free aligned b128 reduce reads.
// ---------------------------------------------------------------------------
__global__ __launch_bounds__(512, 2) void kv_gemm_reduce(const bf16* __restrict__ A,
                                                         const bf16* __restrict__ B,
                                                         const float* __restrict__ p2,
                                                         float* __restrict__ partials) {
  __shared__ __align__(16) bf16 sh[73728];   // 144 KB staging; epilogue aliases
  __shared__ float red[4][2][64];

  const int lin  = blockIdx.y * 6 + blockIdx.x;
  const int xcd  = lin & 7;
  const int j    = lin >> 3;                 // 0..95
  const int hh   = j % 6;
  const int mblk = xcd + 8 * (j / 6);        // 0..127, bijective
  const int m0   = mblk * 256;
  const int h0   = hh * 2;

  const int tid = threadIdx.x, lane = tid & 63, wave = tid >> 6;
  const int ck = ((lane & 3) ^ ((lane >> 3) & 3)) * 8;   // pre-swizzled src chunk
  const bf16* gsrc;
  if (wave < 4) {
    gsrc = A + (size_t)(m0 + wave * 64 + (lane >> 2)) * 768 + ck;
  } else {
    // B tile rows: 64-row segment per wave: [k_h0 | v_h0 | k_h1 | v_h1]
    const int w1 = wave - 4;
    const int wrow = 768 + (w1 & 1) * 768 + (h0 + (w1 >> 1)) * 64 + (lane >> 2);
    gsrc = B + (size_t)wrow * 768 + ck;
  }

  f32x4 acc[8][4] = {};
  gemm256(gsrc, sh, acc);

  // ---- transposed spill: shT[c][n], stride 264, block-XOR on 8-elem n-blocks
  const int wm = wave >> 2, wn = wave & 3, l16 = lane & 15;
  const int c0 = wn * 64 + l16;                 // + ni*16
  const int r0 = wm * 128 + (lane >> 4) * 4;    // + mi*16
#pragma unroll
  for (int ni = 0; ni < 4; ++ni) {
    const int c   = c0 + ni * 16;
    const int key = (c ^ (c >> 3)) & 7;
#pragma unroll
    for (int mi = 0; mi < 8; ++mi) {
      const int r = r0 + mi * 16;
      bf16x4 pk;
      pk[0] = (bf16)acc[mi][ni][0]; pk[1] = (bf16)acc[mi][ni][1];
      pk[2] = (bf16)acc[mi][ni][2]; pk[3] = (bf16)acc[mi][ni][3];
      *(bf16x4*)(sh + (size_t)c * 264 + (((r >> 3) ^ key) << 3) + (r & 7)) = pk;
    }
  }
  __syncthreads();

  // ---- reduce over n: thread (nq 0..3, hl 0..1, d 0..63), 64 n's each, b128
  const int nq = tid >> 7, hl = (tid >> 6) & 1, d = tid & 63;
  const float4* pw4 = (const float4*)(p2 + (size_t)(h0 + hl) * 4096 + (m0 & 4095) + nq * 64);
  const int ck_  = hl * 128 + d;                 // k column
  const int cv_  = ck_ + 64;                     // v column
  const int keyk = (ck_ ^ (ck_ >> 3)) & 7;
  const int keyv = (cv_ ^ (cv_ >> 3)) & 7;
  const bf16* bk = sh + (size_t)ck_ * 264;
  const bf16* bv = sh + (size_t)cv_ * 264;
  float s = 0.f;
#pragma unroll
  for (int nb = 0; nb < 8; ++nb) {
    const int blk = nq * 8 + nb;
    const bf16x8 k8 = *(const bf16x8*)(bk + ((blk ^ keyk) << 3));
    const bf16x8 v8 = *(const bf16x8*)(bv + ((blk ^ keyv) << 3));
    const float4 w0 = pw4[nb * 2];
    const float4 w1 = pw4[nb * 2 + 1];
    s += w0.x * (float)k8[0] * (float)v8[0] + w0.y * (float)k8[1] * (float)v8[1]
       + w0.z * (float)k8[2] * (float)v8[2] + w0.w * (float)k8[3] * (float)v8[3]
       + w1.x * (float)k8[4] * (float)v8[4] + w1.y * (float)k8[5] * (float)v8[5]
       + w1.z * (float)k8[6] * (float)v8[6] + w1.w * (float)k8[7] * (float)v8[7];
  }
  red[nq][hl][d] = s;
  __syncthreads();
  if (tid < 128) {
    const int hx = tid >> 6, dd = tid & 63;
    partials[((size_t)mblk * 12 + h0 + hx) * 64 + dd] =
        red[0][hx][dd] + red[1][hx][dd] + red[2][hx][dd] + red[3][hx][dd];
  }
}

// ---------------------------------------------------------------------------
// Stage 2: sum the 16 per-mblk partials of each batch, then LayerNorm over d.
// grid (12 h, 8 b); 64 threads, d = lane.
// ---------------------------------------------------------------------------
__global__ __launch_bounds__(64) void mod_reduce_ln(const float* __restrict__ partials,
                                                    const float* __restrict__ gamma,
                                                    const float* __restrict__ beta,
                                                    float* __restrict__ mod) {
  const int h = blockIdx.x, b = blockIdx.y;
  const int d = threadIdx.x;

  const float* p = partials + ((size_t)(b * 16) * 12 + h) * 64 + d;
  float s = 0.f;
#pragma unroll
  for (int mb = 0; mb < 16; ++mb) s += p[(size_t)mb * 12 * 64];

  float sum = s, sumsq = s * s;
#pragma unroll
  for (int o = 32; o > 0; o >>= 1) {
    sum   += __shfl_xor(sum, o);
    sumsq += __shfl_xor(sumsq, o);
  }
  const float mu  = sum * (1.f / 64.f);
  const float var = sumsq * (1.f / 64.f) - mu * mu;
  const float r   = rsqrtf(var + LN_EPS);
  mod[(b * 12 + h) * 64 + d] = (s - mu) * r * gamma[d] + beta[d];
}

// ---------------------------------------------------------------------------
// Pass 2: q GEMM + fused modulation. Grid (3, 128) = 384.
// XCD clustering: 3 nblk-sharers of each mblk consecutive on one XCD.
// amod[m, c] = q[m, c] * p1[h(c), n(m)] * mod[b(m), c]  (bf16 out)
// ---------------------------------------------------------------------------
__global__ __launch_bounds__(512, 2) void q_gemm_mod(const bf16* __restrict__ A,
                                                     const bf16* __restrict__ B,
                                                     const float* __restrict__ p1,
                                                     const float* __restrict__ mod,
                                                     bf16* __restrict__ amod) {
  __shared__ __align__(16) bf16 sh[73728];

  const int lin  = blockIdx.y * 3 + blockIdx.x;
  const int xcd  = lin & 7;
  const int j    = lin >> 3;                 // 0..47
  const int nblk = j % 3;
  const int mblk = xcd + 8 * (j / 3);        // 0..127
  const int n0   = nblk * 256;
  const int m0   = mblk * 256;

  const int tid = threadIdx.x, lane = tid & 63, wave = tid >> 6;
  const int ck = ((lane & 3) ^ ((lane >> 3) & 3)) * 8;
  const bf16* gsrc;
  if (wave < 4) gsrc = A + (size_t)(m0 + wave * 64 + (lane >> 2)) * 768 + ck;
  else          gsrc = B + (size_t)(n0 + (wave - 4) * 64 + (lane >> 2)) * 768 + ck;

  f32x4 acc[8][4] = {};
  gemm256(gsrc, sh, acc);

  const int wm = wave >> 2, wn = wave & 3, l16 = lane & 15;
  const int row0 = m0 + wm * 128 + (lane >> 4) * 4;
  const int col0 = n0 + wn * 64 + l16;
  const int b    = m0 >> 12;
  const int h    = (n0 >> 6) + wn;             // wave-uniform head

  float p1v[8][4];
#pragma unroll
  for (int mi = 0; mi < 8; ++mi)
#pragma unroll
    for (int r = 0; r < 4; ++r)
      p1v[mi][r] = p1[(size_t)h * 4096 + ((row0 + mi * 16 + r) & 4095)];
  float mv[4];
#pragma unroll
  for (int ni = 0; ni < 4; ++ni) mv[ni] = mod[b * 768 + col0 + ni * 16];

#pragma unroll
  for (int mi = 0; mi < 8; ++mi)
#pragma unroll
    for (int ni = 0; ni < 4; ++ni)
#pragma unroll
      for (int r = 0; r < 4; ++r)
        amod[(size_t)(row0 + mi * 16 + r) * 768 + col0 + ni * 16] =
            (bf16)(acc[mi][ni][r] * p1v[mi][r] * mv[ni]);
}

// ---------------------------------------------------------------------------
// Pass 3: out[32768,768] fp32 = amod @ w_proj_bf16^T + b_proj. Grid (3, 128).
// ---------------------------------------------------------------------------
__global__ __launch_bounds__(512, 2) void gemm_proj(const bf16* __restrict__ A,
                                                    const bf16* __restrict__ B,
                                                    const float* __restrict__ bias,
                                                    float* __restrict__ C) {
  __shared__ __align__(16) bf16 sh[73728];

  const int lin  = blockIdx.y * 3 + blockIdx.x;
  const int xcd  = lin & 7;
  const int j    = lin >> 3;
  const int nblk = j % 3;
  const int mblk = xcd + 8 * (j / 3);
  const int n0   = nblk * 256;
  const int m0   = mblk * 256;

  const int tid = threadIdx.x, lane = tid & 63, wave = tid >> 6;
  const int ck = ((lane & 3) ^ ((lane >> 3) & 3)) * 8;
  const bf16* gsrc;
  if (wave < 4) gsrc = A + (size_t)(m0 + wave * 64 + (lane >> 2)) * 768 + ck;
  else          gsrc = B + (size_t)(n0 + (wave - 4) * 64 + (lane >> 2)) * 768 + ck;

  f32x4 acc[8][4] = {};
  gemm256(gsrc, sh, acc);

  const int wm = wave >> 2, wn = wave & 3, l16 = lane & 15;
  const int row0 = m0 + wm * 128 + (lane >> 4) * 4;
  const int col0 = n0 + wn * 64 + l16;
#pragma unroll
  for (int ni = 0; ni < 4; ++ni) {
    const int col = col0 + ni * 16;
    const float bv = bias[col];
#pragma unroll
    for (int mi = 0; mi < 8; ++mi)
#pragma unroll
      for (int r = 0; r < 4; ++r)
        C[(size_t)(row0 + mi * 16 + r) * 768 + col] = acc[mi][ni][r] + bv;
  }
}

// ---------------------------------------------------------------------------
extern "C" void kernel_launch(void* const* d_in, const int* in_sizes, int n_in,
                              void* d_out, int out_size, void* d_ws, size_t ws_size,
                              hipStream_t stream) {
  (void)in_sizes; (void)n_in; (void)out_size; (void)ws_size;

  const float* x      = (const float*)d_in[0];   // [8,4096,768]
  const float* w_qkv  = (const float*)d_in[1];   // [2304,768]
  const float* w_proj = (const float*)d_in[2];   // [768,768]
  const float* b_proj = (const float*)d_in[3];   // [768]
  const float* p1     = (const float*)d_in[4];   // [12,4096]
  const float* p2     = (const float*)d_in[5];   // [12,4096]
  const float* gamma  = (const float*)d_in[6];   // [64]
  const float* beta   = (const float*)d_in[7];   // [64]
  float* out = (float*)d_out;                    // [8,4096,768] fp32

  char* ws = (char*)d_ws;
  bf16*  xb       = (bf16*)(ws + 0);              // 50,331,648  x bf16 [32768,768]
  bf16*  wqb      = (bf16*)(ws + 50331648);       //  3,538,944  w_qkv bf16
  bf16*  wpb      = (bf16*)(ws + 53870592);       //  1,179,648  w_proj bf16
  bf16*  amod     = (bf16*)(ws + 55050240);       // 50,331,648  amod bf16 [32768,768]
  float* partials = (float*)(ws + 105381888);     //    393,216  [128][12][64] f32
  float* mod      = (float*)(ws + 106168320);     //     24,576  [8][12][64] f32

  // 1) all fp32 -> bf16 conversions in one launch (26,880 blocks exact)
  cvt_all<<<26880, 256, 0, stream>>>(x, w_qkv, w_proj, xb, wqb, wpb);

  // 2) k/v GEMM + fused p2*k*v reduction (k,v never written to HBM)
  kv_gemm_reduce<<<dim3(6, 128), 512, 0, stream>>>(xb, wqb, p2, partials);

  // 3) finish reduction + LayerNorm -> mod [8,12,64]
  mod_reduce_ln<<<dim3(12, 8), 64, 0, stream>>>(partials, gamma, beta, mod);

  // 4) q GEMM + fused p1/mod modulation -> amod bf16
  q_gemm_mod<<<dim3(3, 128), 512, 0, stream>>>(xb, wqb, p1, mod, amod);

  // 5) proj GEMM + bias -> out fp32
  gemm_proj<<<dim3(3, 128), 512, 0, stream>>>(amod, wpb, b_proj, out);
}

// Round 7
// 372.782 us; speedup vs baseline: 1.0448x; 1.0448x over previous
//
#include <hip/hip_runtime.h>
#include <stdint.h>
#include <stddef.h>

#define LN_EPS 1e-5f

typedef __bf16 bf16;
typedef __bf16 bf16x8 __attribute__((ext_vector_type(8)));
typedef __bf16 bf16x4 __attribute__((ext_vector_type(4)));
typedef float f32x4 __attribute__((ext_vector_type(4)));

// async global->LDS, 16B per lane. LDS dest must be wave-uniform base + lane*16.
#define GL16(gp, lp)                                                                   \
  __builtin_amdgcn_global_load_lds((__attribute__((address_space(1))) uint32_t*)(gp),  \
                                   (__attribute__((address_space(3))) uint32_t*)(lp),  \
                                   16, 0, 0)

#define SBAR   asm volatile("s_barrier" ::: "memory")
#define VMW(N) asm volatile("s_waitcnt vmcnt(" #N ")" ::: "memory")
#define LGK(N) asm volatile("s_waitcnt lgkmcnt(" #N ")" ::: "memory")
#define SCB    __builtin_amdgcn_sched_barrier(0)
#define SP1    __builtin_amdgcn_s_setprio(1)
#define SP0    __builtin_amdgcn_s_setprio(0)
#define NOWAIT ((void)0)

// ---------------------------------------------------------------------------
// single fp32 -> bf16 convert kernel for all three tensors (one launch)
// ---------------------------------------------------------------------------
#define XV4   6291456           // x:      25,165,824 f32 / 4
#define WQV4  442368            // w_qkv:   1,769,472 f32 / 4
#define WPV4  147456            // w_proj:    589,824 f32 / 4
__global__ __launch_bounds__(256) void cvt_all(const float* __restrict__ x,
                                               const float* __restrict__ wq,
                                               const float* __restrict__ wp,
                                               bf16* __restrict__ xb,
                                               bf16* __restrict__ wqb,
                                               bf16* __restrict__ wpb) {
  int i = blockIdx.x * 256 + threadIdx.x;
  const float* src; bf16* dst; int off;
  if (i < XV4)              { src = x;  dst = xb;  off = i; }
  else if (i < XV4 + WQV4)  { src = wq; dst = wqb; off = i - XV4; }
  else                      { src = wp; dst = wpb; off = i - (XV4 + WQV4); }
  const float4 v = ((const float4*)src)[off];
  bf16x4 o;
  o[0] = (bf16)v.x; o[1] = (bf16)v.y; o[2] = (bf16)v.z; o[3] = (bf16)v.w;
  ((bf16x4*)dst)[off] = o;
}

// ---------------------------------------------------------------------------
// m201-template port (loop-rolled): 256x256 tile, BK=64, 8 waves (2M x 4N),
// 8 phases / 2 K-tiles, TWO barriers per phase with post-barrier lgkmcnt(0),
// half-tile (128x64 = 16KB) staging 1 per phase, 2-dbuf LDS (tile t -> dbuf
// t&1), vmcnt checkpoint ONLY at phases 4/8.  K = 768 -> 12 tiles, 6 iters
// (first/last peeled, middle 4 in a no-unroll loop to cut code size 3x).
//
// LDS: A[2 dbuf][2 Mhalf][128][64] + B[2 dbuf][2 Nhalf][128][64] = 128 KB.
// Swizzle: within a row (8 chunks of 16B), LDS chunk-pos cp holds global
// chunk cp ^ (row&7); applied on the GL16 global SOURCE col (dest linear)
// and the ds_read col -> conflict-free ds_read_b128 (both-sides involution).
// Reads per phase: p1/p5: 8 aF + 4 bF (lgk(8) throttle); p2/p6: 4 bF;
// p3/p7: 8 aF; p4/p8: 0 (register reuse).  16 MFMA per phase = one
// C-quadrant (4 Mfrag x 2 Nfrag x 2 ksteps).
//
// Stage plan (iter, T even): p1: A(T+1,h0)  p2: A(T+1,h1)  p3: B(T+2,h0)
//  p4: B(T+2,h1)  p5: A(T+2,h0)  p6: A(T+2,h1)  p7: B(T+3,h0)  p8: B(T+3,h1)
// Overwrite safety (slot last-read -> stage): A(T+1) freed p7 of prev iter;
// B(T+2) freed p2; A(T+2) freed p3; B(T+3) freed p6 -- all barrier-separated.
// vmcnt ledger (2 GL16/stage): p4-end outstanding = 12 -> VMW(4) completes
// tile T+1 (read p5-p8); p8-end outstanding = 12 -> VMW(4) completes tile
// T+2 (read next p1-p4).  Wait-then-barrier publishes per-wave GL16
// completions to all waves.  Prologue: tiles 0,1 staged (16 GL16), VMW(8)
// -> tile 0 resident.  Tail iter (tiles 10,11): only p1,p2 stages; VMW(0).
// ---------------------------------------------------------------------------
#define STAGE_A(T, H) do {                                              \
    bf16* d_ = ldsA + ((((T)&1) << 1) + (H)) * 8192 + tid8;             \
    GL16(pA + (H) * 98304 + (T) * 64, d_);                              \
    GL16(pA + (H) * 98304 + 49152 + (T) * 64, d_ + 4096); } while (0)

#define STAGE_B(T, H) do {                                              \
    bf16* d_ = ldsB + ((((T)&1) << 1) + (H)) * 8192 + tid8;             \
    GL16(pB##H##0 + (T) * 64, d_);                                      \
    GL16(pB##H##1 + (T) * 64, d_ + 4096); } while (0)

#define RD_AQ(D, MQ) do {                                               \
    _Pragma("unroll") for (int mf = 0; mf < 4; ++mf) {                  \
      const int r_ = (MQ) * 64 + mf * 16 + l16;                         \
      const bf16* b_ = ldsA + (((D) << 1) + wm) * 8192 + r_ * 64;       \
      const int x_ = r_ & 7;                                            \
      aF[mf][0] = *(const bf16x8*)(b_ + ((qg ^ x_) << 3));              \
      aF[mf][1] = *(const bf16x8*)(b_ + (((4 + qg) ^ x_) << 3));        \
    } } while (0)

#define RD_BQ(D, NQ, BF) do {                                           \
    _Pragma("unroll") for (int nf = 0; nf < 2; ++nf) {                  \
      const int r_ = hn64 + (NQ) * 32 + nf * 16 + l16;                  \
      const bf16* b_ = ldsB + (((D) << 1) + hb) * 8192 + r_ * 64;       \
      const int x_ = r_ & 7;                                            \
      BF[nf][0] = *(const bf16x8*)(b_ + ((qg ^ x_) << 3));              \
      BF[nf][1] = *(const bf16x8*)(b_ + (((4 + qg) ^ x_) << 3));        \
    } } while (0)

#define MMQ(MQ, NQ, BF) do {                                            \
    _Pragma("unroll") for (int mf = 0; mf < 4; ++mf)                    \
      _Pragma("unroll") for (int nf = 0; nf < 2; ++nf) {                \
        acc[(MQ)*4+mf][(NQ)*2+nf] = __builtin_amdgcn_mfma_f32_16x16x32_bf16( \
            aF[mf][0], BF[nf][0], acc[(MQ)*4+mf][(NQ)*2+nf], 0, 0, 0);  \
        acc[(MQ)*4+mf][(NQ)*2+nf] = __builtin_amdgcn_mfma_f32_16x16x32_bf16( \
            aF[mf][1], BF[nf][1], acc[(MQ)*4+mf][(NQ)*2+nf], 0, 0, 0);  \
      } } while (0)

#define ITER(T, P12, P38, WV4, WV8) do {                                       \
    /* p1 */ RD_AQ(0, 0); RD_BQ(0, 0, bF0); if (P12) STAGE_A((T)+1, 0); LGK(8);\
    SBAR; LGK(0); SCB; SP1; MMQ(0, 0, bF0); SP0; SBAR;                         \
    /* p2 */ RD_BQ(0, 1, bF1); if (P12) STAGE_A((T)+1, 1);                     \
    SBAR; LGK(0); SCB; SP1; MMQ(0, 1, bF1); SP0; SBAR;                         \
    /* p3 */ RD_AQ(0, 1); if (P38) STAGE_B((T)+2, 0);                          \
    SBAR; LGK(0); SCB; SP1; MMQ(1, 0, bF0); SP0; SBAR;                         \
    /* p4 */ if (P38) STAGE_B((T)+2, 1);                                       \
    SBAR; LGK(0); SCB; SP1; MMQ(1, 1, bF1); SP0; WV4; SBAR;                    \
    /* p5 */ RD_AQ(1, 0); RD_BQ(1, 0, bF0); if (P38) STAGE_A((T)+2, 0); LGK(8);\
    SBAR; LGK(0); SCB; SP1; MMQ(0, 0, bF0); SP0; SBAR;                         \
    /* p6 */ RD_BQ(1, 1, bF1); if (P38) STAGE_A((T)+2, 1);                     \
    SBAR; LGK(0); SCB; SP1; MMQ(0, 1, bF1); SP0; SBAR;                         \
    /* p7 */ RD_AQ(1, 1); if (P38) STAGE_B((T)+3, 0);                          \
    SBAR; LGK(0); SCB; SP1; MMQ(1, 0, bF0); SP0; SBAR;                         \
    /* p8 */ if (P38) STAGE_B((T)+3, 1);                                       \
    SBAR; LGK(0); SCB; SP1; MMQ(1, 1, bF1); SP0; WV8; SBAR;                    \
  } while (0)

__device__ __forceinline__ void gemm256(const bf16* pA,
                                        const bf16* pB00, const bf16* pB01,
                                        const bf16* pB10, const bf16* pB11,
                                        bf16* sh, f32x4 acc[8][4]) {
  const int tid  = threadIdx.x;
  const int lane = tid & 63;
  const int wave = tid >> 6;
  const int wm   = wave >> 2;          // 0..1  (A half = M half)
  const int wn   = wave & 3;           // 0..3
  const int hb   = wn >> 1;            // B half (N half)
  const int hn64 = (wn & 1) * 64;      // row offset inside B half
  const int l16  = lane & 15;
  const int qg   = lane >> 4;          // 0..3, k-chunk group
  const int tid8 = tid * 8;            // GL16 dest: wave-uniform + lane*16B
  bf16* const ldsA = sh;               // [2][2][128][64] = 64 KB
  bf16* const ldsB = sh + 32768;       // [2][2][128][64] = 64 KB
  bf16x8 aF[4][2], bF0[2][2], bF1[2][2];

  // prologue: tiles 0,1 fully staged (16 GL16); VMW(8) -> tile 0 resident.
  STAGE_A(0, 0); STAGE_A(0, 1); STAGE_B(0, 0); STAGE_B(0, 1);
  STAGE_A(1, 0); STAGE_A(1, 1); STAGE_B(1, 0); STAGE_B(1, 1);
  VMW(8);
  SBAR;

  ITER(0, 0, 1, VMW(4), VMW(4));    // A(1) pre-staged -> skip p1,p2 stages
#pragma unroll 1
  for (int T = 2; T <= 8; T += 2) { // middle iters, loop-rolled (code size)
    ITER(T, 1, 1, VMW(4), VMW(4));
  }
  ITER(10, 1, 0, VMW(0), NOWAIT);   // stages only A(11); drain at p4

  __syncthreads();
}

// ---------------------------------------------------------------------------
// Pass 1: k/v GEMM + fused p2-weighted k*v reduction. Grid (6, 128) = 768.
// XCD clustering: 6 hh-blocks sharing an A mblk-tile consecutive on one XCD.
// B cols spliced [k_h0 | v_h0 | k_h1 | v_h1]: each (Nhalf, piece) is exactly
// one 64-row w_qkv segment -> 4 precomputed row-base pointers.
// Epilogue: padded spill sh[256][260] (0-conflict class): write banks =
// 4 row-groups x 8 col-dwords = all 32; reduce reads 64 lanes span 64
// consecutive cols = 32 dwords -> conflict-free.
// ---------------------------------------------------------------------------
__global__ __launch_bounds__(512, 2) void kv_gemm_reduce(const bf16* __restrict__ A,
                                                         const bf16* __restrict__ B,
                                                         const float* __restrict__ p2,
                                                         float* __restrict__ partials) {
  __shared__ __align__(16) bf16 sh[66560];     // max(staging 65536, spill 256*260)
  __shared__ float red[4][2][64];

  const int lin  = blockIdx.y * 6 + blockIdx.x;
  const int xcd  = lin & 7;
  const int j    = lin >> 3;                 // 0..95
  const int hh   = j % 6;
  const int mblk = xcd + 8 * (j / 6);        // 0..127, bijective
  const int m0   = mblk * 256;
  const int h0   = hh * 2;

  const int tid = threadIdx.x;
  const int tr  = tid >> 3;                                // piece-row 0..63
  const int tc  = ((tid & 7) ^ ((tid >> 3) & 7)) * 8;      // pre-swizzled col
  const bf16* pA   = A + (size_t)(m0 + tr) * 768 + tc;
  const bf16* pB00 = B + (size_t)(768  + (h0 + 0) * 64 + tr) * 768 + tc;  // k_h0
  const bf16* pB01 = B + (size_t)(1536 + (h0 + 0) * 64 + tr) * 768 + tc;  // v_h0
  const bf16* pB10 = B + (size_t)(768  + (h0 + 1) * 64 + tr) * 768 + tc;  // k_h1
  const bf16* pB11 = B + (size_t)(1536 + (h0 + 1) * 64 + tr) * 768 + tc;  // v_h1

  f32x4 acc[8][4] = {};
  gemm256(pA, pB00, pB01, pB10, pB11, sh, acc);

  // ---- spill C[256 m][256 kv-col] as bf16, stride 260 (padded, 0-conflict)
  const int lane = tid & 63, wave = tid >> 6;
  const int wm = wave >> 2, wn = wave & 3, l16 = lane & 15, qg = lane >> 4;
  const int r0s = wm * 128 + qg * 4;
  const int c0s = wn * 64 + l16;
#pragma unroll
  for (int mi = 0; mi < 8; ++mi)
#pragma unroll
    for (int ni = 0; ni < 4; ++ni)
#pragma unroll
      for (int r = 0; r < 4; ++r)
        sh[(size_t)(r0s + mi * 16 + r) * 260 + c0s + ni * 16] = (bf16)acc[mi][ni][r];
  __syncthreads();

  // ---- reduce over m: thread (nq 0..3, hl 0..1, d 0..63), 64 rows each
  const int nq = tid >> 7, hl = (tid >> 6) & 1, d = tid & 63;
  const float4* pw4 = (const float4*)(p2 + (size_t)(h0 + hl) * 4096 + (m0 & 4095) + nq * 64);
  const bf16* pk = sh + (size_t)(nq * 64) * 260 + hl * 128 + d;
  const bf16* pv = pk + 64;
  float s = 0.f;
#pragma unroll
  for (int nb = 0; nb < 16; ++nb) {
    const float4 w = pw4[nb];
    const int n = nb * 4;
    s += w.x * (float)pk[(n + 0) * 260] * (float)pv[(n + 0) * 260]
       + w.y * (float)pk[(n + 1) * 260] * (float)pv[(n + 1) * 260]
       + w.z * (float)pk[(n + 2) * 260] * (float)pv[(n + 2) * 260]
       + w.w * (float)pk[(n + 3) * 260] * (float)pv[(n + 3) * 260];
  }
  red[nq][hl][d] = s;
  __syncthreads();
  if (tid < 128) {
    const int hx = tid >> 6, dd = tid & 63;
    partials[((size_t)mblk * 12 + h0 + hx) * 64 + dd] =
        red[0][hx][dd] + red[1][hx][dd] + red[2][hx][dd] + red[3][hx][dd];
  }
}

// ---------------------------------------------------------------------------
// Stage 2: sum the 16 per-mblk partials of each batch, then LayerNorm over d.
// grid (12 h, 8 b); 64 threads, d = lane.
// ---------------------------------------------------------------------------
__global__ __launch_bounds__(64) void mod_reduce_ln(const float* __restrict__ partials,
                                                    const float* __restrict__ gamma,
                                                    const float* __restrict__ beta,
                                                    float* __restrict__ mod) {
  const int h = blockIdx.x, b = blockIdx.y;
  const int d = threadIdx.x;

  const float* p = partials + ((size_t)(b * 16) * 12 + h) * 64 + d;
  float s = 0.f;
#pragma unroll
  for (int mb = 0; mb < 16; ++mb) s += p[(size_t)mb * 12 * 64];

  float sum = s, sumsq = s * s;
#pragma unroll
  for (int o = 32; o > 0; o >>= 1) {
    sum   += __shfl_xor(sum, o);
    sumsq += __shfl_xor(sumsq, o);
  }
  const float mu  = sum * (1.f / 64.f);
  const float var = sumsq * (1.f / 64.f) - mu * mu;
  const float r   = rsqrtf(var + LN_EPS);
  mod[(b * 12 + h) * 64 + d] = (s - mu) * r * gamma[d] + beta[d];
}

// ---------------------------------------------------------------------------
// Pass 2: q GEMM + fused modulation. Grid (3, 128) = 384.
// amod[m, c] = q[m, c] * p1[h(c), n(m)] * mod[b(m), c]  (bf16 out)
// ---------------------------------------------------------------------------
__global__ __launch_bounds__(512, 2) void q_gemm_mod(const bf16* __restrict__ A,
                                                     const bf16* __restrict__ B,
                                                     const float* __restrict__ p1,
                                                     const float* __restrict__ mod,
                                                     bf16* __restrict__ amod) {
  __shared__ __align__(16) bf16 sh[65536];

  const int lin  = blockIdx.y * 3 + blockIdx.x;
  const int xcd  = lin & 7;
  const int j    = lin >> 3;                 // 0..47
  const int nblk = j % 3;
  const int mblk = xcd + 8 * (j / 3);        // 0..127
  const int n0   = nblk * 256;
  const int m0   = mblk * 256;

  const int tid = threadIdx.x;
  const int tr  = tid >> 3;
  const int tc  = ((tid & 7) ^ ((tid >> 3) & 7)) * 8;
  const bf16* pA   = A + (size_t)(m0 + tr) * 768 + tc;
  const bf16* pB00 = B + (size_t)(n0 + tr) * 768 + tc;
  const bf16* pB01 = pB00 + (size_t)64 * 768;
  const bf16* pB10 = pB00 + (size_t)128 * 768;
  const bf16* pB11 = pB00 + (size_t)192 * 768;

  f32x4 acc[8][4] = {};
  gemm256(pA, pB00, pB01, pB10, pB11, sh, acc);

  const int lane = tid & 63, wave = tid >> 6;
  const int wm = wave >> 2, wn = wave & 3, l16 = lane & 15;
  const int row0 = m0 + wm * 128 + (lane >> 4) * 4;
  const int col0 = n0 + wn * 64 + l16;
  const int b    = m0 >> 12;
  const int h    = (n0 >> 6) + wn;             // wave-uniform head

  float p1v[8][4];
#pragma unroll
  for (int mi = 0; mi < 8; ++mi)
#pragma unroll
    for (int r = 0; r < 4; ++r)
      p1v[mi][r] = p1[(size_t)h * 4096 + ((row0 + mi * 16 + r) & 4095)];
  float mv[4];
#pragma unroll
  for (int ni = 0; ni < 4; ++ni) mv[ni] = mod[b * 768 + col0 + ni * 16];

#pragma unroll
  for (int mi = 0; mi < 8; ++mi)
#pragma unroll
    for (int ni = 0; ni < 4; ++ni)
#pragma unroll
      for (int r = 0; r < 4; ++r)
        amod[(size_t)(row0 + mi * 16 + r) * 768 + col0 + ni * 16] =
            (bf16)(acc[mi][ni][r] * p1v[mi][r] * mv[ni]);
}

// ---------------------------------------------------------------------------
// Pass 3: out[32768,768] fp32 = amod @ w_proj_bf16^T + b_proj. Grid (3, 128).
// ---------------------------------------------------------------------------
__global__ __launch_bounds__(512, 2) void gemm_proj(const bf16* __restrict__ A,
                                                    const bf16* __restrict__ B,
                                                    const float* __restrict__ bias,
                                                    float* __restrict__ C) {
  __shared__ __align__(16) bf16 sh[65536];

  const int lin  = blockIdx.y * 3 + blockIdx.x;
  const int xcd  = lin & 7;
  const int j    = lin >> 3;
  const int nblk = j % 3;
  const int mblk = xcd + 8 * (j / 3);
  const int n0   = nblk * 256;
  const int m0   = mblk * 256;

  const int tid = threadIdx.x;
  const int tr  = tid >> 3;
  const int tc  = ((tid & 7) ^ ((tid >> 3) & 7)) * 8;
  const bf16* pA   = A + (size_t)(m0 + tr) * 768 + tc;
  const bf16* pB00 = B + (size_t)(n0 + tr) * 768 + tc;
  const bf16* pB01 = pB00 + (size_t)64 * 768;
  const bf16* pB10 = pB00 + (size_t)128 * 768;
  const bf16* pB11 = pB00 + (size_t)192 * 768;

  f32x4 acc[8][4] = {};
  gemm256(pA, pB00, pB01, pB10, pB11, sh, acc);

  const int lane = tid & 63, wave = tid >> 6;
  const int wm = wave >> 2, wn = wave & 3, l16 = lane & 15;
  const int row0 = m0 + wm * 128 + (lane >> 4) * 4;
  const int col0 = n0 + wn * 64 + l16;
#pragma unroll
  for (int ni = 0; ni < 4; ++ni) {
    const int col = col0 + ni * 16;
    const float bv = bias[col];
#pragma unroll
    for (int mi = 0; mi < 8; ++mi)
#pragma unroll
      for (int r = 0; r < 4; ++r)
        C[(size_t)(row0 + mi * 16 + r) * 768 + col] = acc[mi][ni][r] + bv;
  }
}

// ---------------------------------------------------------------------------
extern "C" void kernel_launch(void* const* d_in, const int* in_sizes, int n_in,
                              void* d_out, int out_size, void* d_ws, size_t ws_size,
                              hipStream_t stream) {
  (void)in_sizes; (void)n_in; (void)out_size; (void)ws_size;

  const float* x      = (const float*)d_in[0];   // [8,4096,768]
  const float* w_qkv  = (const float*)d_in[1];   // [2304,768]
  const float* w_proj = (const float*)d_in[2];   // [768,768]
  const float* b_proj = (const float*)d_in[3];   // [768]
  const float* p1     = (const float*)d_in[4];   // [12,4096]
  const float* p2     = (const float*)d_in[5];   // [12,4096]
  const float* gamma  = (const float*)d_in[6];   // [64]
  const float* beta   = (const float*)d_in[7];   // [64]
  float* out = (float*)d_out;                    // [8,4096,768] fp32

  char* ws = (char*)d_ws;
  bf16*  xb       = (bf16*)(ws + 0);              // 50,331,648  x bf16 [32768,768]
  bf16*  wqb      = (bf16*)(ws + 50331648);       //  3,538,944  w_qkv bf16
  bf16*  wpb      = (bf16*)(ws + 53870592);       //  1,179,648  w_proj bf16
  bf16*  amod     = (bf16*)(ws + 55050240);       // 50,331,648  amod bf16 [32768,768]
  float* partials = (float*)(ws + 105381888);     //    393,216  [128][12][64] f32
  float* mod      = (float*)(ws + 106168320);     //     24,576  [8][12][64] f32

  // 1) all fp32 -> bf16 conversions in one launch (26,880 blocks exact)
  cvt_all<<<26880, 256, 0, stream>>>(x, w_qkv, w_proj, xb, wqb, wpb);

  // 2) k/v GEMM + fused p2*k*v reduction (k,v never written to HBM)
  kv_gemm_reduce<<<dim3(6, 128), 512, 0, stream>>>(xb, wqb, p2, partials);

  // 3) finish reduction + LayerNorm -> mod [8,12,64]
  mod_reduce_ln<<<dim3(12, 8), 64, 0, stream>>>(partials, gamma, beta, mod);

  // 4) q GEMM + fused p1/mod modulation -> amod bf16
  q_gemm_mod<<<dim3(3, 128), 512, 0, stream>>>(xb, wqb, p1, mod, amod);

  // 5) proj GEMM + bias -> out fp32
  gemm_proj<<<dim3(3, 128), 512, 0, stream>>>(amod, wpb, b_proj, out);
}

// Round 8
// 355.595 us; speedup vs baseline: 1.0953x; 1.0483x over previous
//
#include <hip/hip_runtime.h>
#include <stdint.h>
#include <stddef.h>

#define LN_EPS 1e-5f

typedef __bf16 bf16;
typedef __bf16 bf16x8 __attribute__((ext_vector_type(8)));
typedef __bf16 bf16x4 __attribute__((ext_vector_type(4)));
typedef float f32x4 __attribute__((ext_vector_type(4)));

// async global->LDS, 16B per lane. LDS dest must be wave-uniform base + lane*16.
#define GL16(gp, lp)                                                                   \
  __builtin_amdgcn_global_load_lds((__attribute__((address_space(1))) uint32_t*)(gp),  \
                                   (__attribute__((address_space(3))) uint32_t*)(lp),  \
                                   16, 0, 0)

#define SBAR   asm volatile("s_barrier" ::: "memory")
#define VMW(N) asm volatile("s_waitcnt vmcnt(" #N ")" ::: "memory")
#define LGK(N) asm volatile("s_waitcnt lgkmcnt(" #N ")" ::: "memory")
#define SCB    __builtin_amdgcn_sched_barrier(0)
#define SP1    __builtin_amdgcn_s_setprio(1)
#define SP0    __builtin_amdgcn_s_setprio(0)
#define NOWAIT ((void)0)

// ---------------------------------------------------------------------------
// single fp32 -> bf16 convert kernel for all three tensors (one launch)
// ---------------------------------------------------------------------------
#define XV4   6291456           // x:      25,165,824 f32 / 4
#define WQV4  442368            // w_qkv:   1,769,472 f32 / 4
#define WPV4  147456            // w_proj:    589,824 f32 / 4
__global__ __launch_bounds__(256) void cvt_all(const float* __restrict__ x,
                                               const float* __restrict__ wq,
                                               const float* __restrict__ wp,
                                               bf16* __restrict__ xb,
                                               bf16* __restrict__ wqb,
                                               bf16* __restrict__ wpb) {
  int i = blockIdx.x * 256 + threadIdx.x;
  const float* src; bf16* dst; int off;
  if (i < XV4)              { src = x;  dst = xb;  off = i; }
  else if (i < XV4 + WQV4)  { src = wq; dst = wqb; off = i - XV4; }
  else                      { src = wp; dst = wpb; off = i - (XV4 + WQV4); }
  const float4 v = ((const float4*)src)[off];
  bf16x4 o;
  o[0] = (bf16)v.x; o[1] = (bf16)v.y; o[2] = (bf16)v.z; o[3] = (bf16)v.w;
  ((bf16x4*)dst)[off] = o;
}

// ---------------------------------------------------------------------------
// Core A (unchanged r7, measured): 256x256 tile, BK=64, 8 waves (2M x 4N),
// 8 phases / 2 K-tiles, two barriers/phase, half-tile staging, 2-dbuf,
// vmcnt ckpt at p4/p8.  K=768 -> 12 tiles, 6 iters (middle 4 loop-rolled).
// ---------------------------------------------------------------------------
#define STAGE_A(T, H) do {                                              \
    bf16* d_ = ldsA + ((((T)&1) << 1) + (H)) * 8192 + tid8;             \
    GL16(pA + (H) * 98304 + (T) * 64, d_);                              \
    GL16(pA + (H) * 98304 + 49152 + (T) * 64, d_ + 4096); } while (0)

#define STAGE_B(T, H) do {                                              \
    bf16* d_ = ldsB + ((((T)&1) << 1) + (H)) * 8192 + tid8;             \
    GL16(pB##H##0 + (T) * 64, d_);                                      \
    GL16(pB##H##1 + (T) * 64, d_ + 4096); } while (0)

#define RD_AQ(D, MQ) do {                                               \
    _Pragma("unroll") for (int mf = 0; mf < 4; ++mf) {                  \
      const int r_ = (MQ) * 64 + mf * 16 + l16;                         \
      const bf16* b_ = ldsA + (((D) << 1) + wm) * 8192 + r_ * 64;       \
      const int x_ = r_ & 7;                                            \
      aF[mf][0] = *(const bf16x8*)(b_ + ((qg ^ x_) << 3));              \
      aF[mf][1] = *(const bf16x8*)(b_ + (((4 + qg) ^ x_) << 3));        \
    } } while (0)

#define RD_BQ(D, NQ, BF) do {                                           \
    _Pragma("unroll") for (int nf = 0; nf < 2; ++nf) {                  \
      const int r_ = hn64 + (NQ) * 32 + nf * 16 + l16;                  \
      const bf16* b_ = ldsB + (((D) << 1) + hb) * 8192 + r_ * 64;       \
      const int x_ = r_ & 7;                                            \
      BF[nf][0] = *(const bf16x8*)(b_ + ((qg ^ x_) << 3));              \
      BF[nf][1] = *(const bf16x8*)(b_ + (((4 + qg) ^ x_) << 3));        \
    } } while (0)

#define MMQ(MQ, NQ, BF) do {                                            \
    _Pragma("unroll") for (int mf = 0; mf < 4; ++mf)                    \
      _Pragma("unroll") for (int nf = 0; nf < 2; ++nf) {                \
        acc[(MQ)*4+mf][(NQ)*2+nf] = __builtin_amdgcn_mfma_f32_16x16x32_bf16( \
            aF[mf][0], BF[nf][0], acc[(MQ)*4+mf][(NQ)*2+nf], 0, 0, 0);  \
        acc[(MQ)*4+mf][(NQ)*2+nf] = __builtin_amdgcn_mfma_f32_16x16x32_bf16( \
            aF[mf][1], BF[nf][1], acc[(MQ)*4+mf][(NQ)*2+nf], 0, 0, 0);  \
      } } while (0)

#define ITER(T, P12, P38, WV4, WV8) do {                                       \
    /* p1 */ RD_AQ(0, 0); RD_BQ(0, 0, bF0); if (P12) STAGE_A((T)+1, 0); LGK(8);\
    SBAR; LGK(0); SCB; SP1; MMQ(0, 0, bF0); SP0; SBAR;                         \
    /* p2 */ RD_BQ(0, 1, bF1); if (P12) STAGE_A((T)+1, 1);                     \
    SBAR; LGK(0); SCB; SP1; MMQ(0, 1, bF1); SP0; SBAR;                         \
    /* p3 */ RD_AQ(0, 1); if (P38) STAGE_B((T)+2, 0);                          \
    SBAR; LGK(0); SCB; SP1; MMQ(1, 0, bF0); SP0; SBAR;                         \
    /* p4 */ if (P38) STAGE_B((T)+2, 1);                                       \
    SBAR; LGK(0); SCB; SP1; MMQ(1, 1, bF1); SP0; WV4; SBAR;                    \
    /* p5 */ RD_AQ(1, 0); RD_BQ(1, 0, bF0); if (P38) STAGE_A((T)+2, 0); LGK(8);\
    SBAR; LGK(0); SCB; SP1; MMQ(0, 0, bF0); SP0; SBAR;                         \
    /* p6 */ RD_BQ(1, 1, bF1); if (P38) STAGE_A((T)+2, 1);                     \
    SBAR; LGK(0); SCB; SP1; MMQ(0, 1, bF1); SP0; SBAR;                         \
    /* p7 */ RD_AQ(1, 1); if (P38) STAGE_B((T)+3, 0);                          \
    SBAR; LGK(0); SCB; SP1; MMQ(1, 0, bF0); SP0; SBAR;                         \
    /* p8 */ if (P38) STAGE_B((T)+3, 1);                                       \
    SBAR; LGK(0); SCB; SP1; MMQ(1, 1, bF1); SP0; WV8; SBAR;                    \
  } while (0)

__device__ __forceinline__ void gemm256(const bf16* pA,
                                        const bf16* pB00, const bf16* pB01,
                                        const bf16* pB10, const bf16* pB11,
                                        bf16* sh, f32x4 acc[8][4]) {
  const int tid  = threadIdx.x;
  const int lane = tid & 63;
  const int wave = tid >> 6;
  const int wm   = wave >> 2;
  const int wn   = wave & 3;
  const int hb   = wn >> 1;
  const int hn64 = (wn & 1) * 64;
  const int l16  = lane & 15;
  const int qg   = lane >> 4;
  const int tid8 = tid * 8;
  bf16* const ldsA = sh;               // [2][2][128][64] = 64 KB
  bf16* const ldsB = sh + 32768;       // [2][2][128][64] = 64 KB
  bf16x8 aF[4][2], bF0[2][2], bF1[2][2];

  STAGE_A(0, 0); STAGE_A(0, 1); STAGE_B(0, 0); STAGE_B(0, 1);
  STAGE_A(1, 0); STAGE_A(1, 1); STAGE_B(1, 0); STAGE_B(1, 1);
  VMW(8);
  SBAR;

  ITER(0, 0, 1, VMW(4), VMW(4));
#pragma unroll 1
  for (int T = 2; T <= 8; T += 2) {
    ITER(T, 1, 1, VMW(4), VMW(4));
  }
  ITER(10, 1, 0, VMW(0), NOWAIT);

  asm volatile("s_waitcnt vmcnt(0) lgkmcnt(0)" ::: "memory");
  __syncthreads();
}

// ---------------------------------------------------------------------------
// Core B (new): 128x256 tile, BK=64, 8 waves, per-wave 64x64 (2M x 4N).
// Same 8-phase skeleton; A is a single 128-row stage per K-tile.
// LDS: A[2dbuf][128][64] = 32 KB + B[2dbuf][2Nhalf][128][64] = 64 KB -> 96 KB.
// Stage plan (iter T): p1: A(T+1)  p3: B(T+2,h0)  p4: B(T+2,h1)
//                      p5: A(T+2)  p7: B(T+3,h0)  p8: B(T+3,h1)
// vmcnt ledger (2 GL16/stage): p4-end outstanding = {B(T+1)x2, A(T+1),
// B(T+2)x2} = 10 -> VMW(4) completes tile T+1 (read p5-p8). p8-end
// outstanding = {A(T+2), B(T+3)x2} = 6 -> VMW(4) completes A(T+2) (tile
// T+2's B done earlier).  Prologue: tiles 0,1 = 12 GL16, VMW(6) -> tile 0.
// Tail iter (10): only p1 stages; VMW(0) at p4.  Overwrite hazards all
// barrier-separated (same argument as core A).
// ---------------------------------------------------------------------------
#define QSTAGE_A(T) do {                                          \
    bf16* d_ = qldsA + (((T)&1)) * 8192 + tid8;                   \
    GL16(qA + (T) * 64, d_);                                      \
    GL16(qA + 49152 + (T) * 64, d_ + 4096); } while (0)

#define QSTAGE_B(T, H) do {                                       \
    bf16* d_ = qldsB + ((((T)&1) << 1) + (H)) * 8192 + tid8;      \
    GL16(qB##H##0 + (T) * 64, d_);                                \
    GL16(qB##H##1 + (T) * 64, d_ + 4096); } while (0)

#define QRD_A(D, MQ) do {                                         \
    _Pragma("unroll") for (int mf = 0; mf < 2; ++mf) {            \
      const int r_ = wm * 64 + (MQ) * 32 + mf * 16 + l16;         \
      const bf16* b_ = qldsA + (D) * 8192 + r_ * 64;              \
      const int x_ = r_ & 7;                                      \
      aF[mf][0] = *(const bf16x8*)(b_ + ((qg ^ x_) << 3));        \
      aF[mf][1] = *(const bf16x8*)(b_ + (((4 + qg) ^ x_) << 3));  \
    } } while (0)

#define QRD_B(D, NQ, BF) do {                                     \
    _Pragma("unroll") for (int nf = 0; nf < 2; ++nf) {            \
      const int r_ = hn64 + (NQ) * 32 + nf * 16 + l16;            \
      const bf16* b_ = qldsB + (((D) << 1) + hb) * 8192 + r_ * 64;\
      const int x_ = r_ & 7;                                      \
      BF[nf][0] = *(const bf16x8*)(b_ + ((qg ^ x_) << 3));        \
      BF[nf][1] = *(const bf16x8*)(b_ + (((4 + qg) ^ x_) << 3));  \
    } } while (0)

#define QMM(MQ, NQ, BF) do {                                      \
    _Pragma("unroll") for (int mf = 0; mf < 2; ++mf)              \
      _Pragma("unroll") for (int nf = 0; nf < 2; ++nf) {          \
        acc[(MQ)*2+mf][(NQ)*2+nf] = __builtin_amdgcn_mfma_f32_16x16x32_bf16( \
            aF[mf][0], BF[nf][0], acc[(MQ)*2+mf][(NQ)*2+nf], 0, 0, 0); \
        acc[(MQ)*2+mf][(NQ)*2+nf] = __builtin_amdgcn_mfma_f32_16x16x32_bf16( \
            aF[mf][1], BF[nf][1], acc[(MQ)*2+mf][(NQ)*2+nf], 0, 0, 0); \
      } } while (0)

#define QITER(T, P1, P38, WVp4, WVp8) do {                                     \
    /* p1 */ QRD_A(0, 0); QRD_B(0, 0, bF0); if (P1) QSTAGE_A((T)+1);           \
    SBAR; LGK(0); SCB; SP1; QMM(0, 0, bF0); SP0; SBAR;                         \
    /* p2 */ QRD_B(0, 1, bF1);                                                 \
    SBAR; LGK(0); SCB; SP1; QMM(0, 1, bF1); SP0; SBAR;                         \
    /* p3 */ QRD_A(0, 1); if (P38) QSTAGE_B((T)+2, 0);                         \
    SBAR; LGK(0); SCB; SP1; QMM(1, 0, bF0); SP0; SBAR;                         \
    /* p4 */ if (P38) QSTAGE_B((T)+2, 1);                                      \
    SBAR; LGK(0); SCB; SP1; QMM(1, 1, bF1); SP0; WVp4; SBAR;                   \
    /* p5 */ QRD_A(1, 0); QRD_B(1, 0, bF0); if (P38) QSTAGE_A((T)+2);          \
    SBAR; LGK(0); SCB; SP1; QMM(0, 0, bF0); SP0; SBAR;                         \
    /* p6 */ QRD_B(1, 1, bF1);                                                 \
    SBAR; LGK(0); SCB; SP1; QMM(0, 1, bF1); SP0; SBAR;                         \
    /* p7 */ QRD_A(1, 1); if (P38) QSTAGE_B((T)+3, 0);                         \
    SBAR; LGK(0); SCB; SP1; QMM(1, 0, bF0); SP0; SBAR;                         \
    /* p8 */ if (P38) QSTAGE_B((T)+3, 1);                                      \
    SBAR; LGK(0); SCB; SP1; QMM(1, 1, bF1); SP0; WVp8; SBAR;                   \
  } while (0)

__device__ __forceinline__ void gemm128x256(const bf16* qA,
                                            const bf16* qB00, const bf16* qB01,
                                            const bf16* qB10, const bf16* qB11,
                                            bf16* sh, f32x4 acc[4][4]) {
  const int tid  = threadIdx.x;
  const int lane = tid & 63;
  const int wave = tid >> 6;
  const int wm   = wave >> 2;          // 0..1 (64-row half of 128)
  const int wn   = wave & 3;
  const int hb   = wn >> 1;
  const int hn64 = (wn & 1) * 64;
  const int l16  = lane & 15;
  const int qg   = lane >> 4;
  const int tid8 = tid * 8;
  bf16* const qldsA = sh;              // [2][128][64] = 32 KB
  bf16* const qldsB = sh + 16384;      // [2][2][128][64] = 64 KB
  bf16x8 aF[2][2], bF0[2][2], bF1[2][2];

  QSTAGE_A(0); QSTAGE_B(0, 0); QSTAGE_B(0, 1);
  QSTAGE_A(1); QSTAGE_B(1, 0); QSTAGE_B(1, 1);
  VMW(6);
  SBAR;

  QITER(0, 0, 1, VMW(4), VMW(4));   // A(1) pre-staged
#pragma unroll 1
  for (int T = 2; T <= 8; T += 2) {
    QITER(T, 1, 1, VMW(4), VMW(4));
  }
  QITER(10, 1, 0, VMW(0), NOWAIT);

  asm volatile("s_waitcnt vmcnt(0) lgkmcnt(0)" ::: "memory");
  __syncthreads();
}

// ---------------------------------------------------------------------------
// Pass 1: k/v GEMM + fused p2-weighted reduction, IN-REGISTER epilogue.
// Grid (6, 128) = 768 = 3 exact rounds.  B-tile cols INTERLEAVE k and v per
// head so k[n,d] and v[n,d] land in the same lane:
//   B-tile row r -> (head = r>>7, kv = (r>>4)&1, d = ((r>>5)&3)*16 + (r&15))
//   w_qkv row = 768 + kv*768 + (h0+head)*64 + d      (bijective over 256)
// Epilogue: in acc[ai][bj], bj even = k, bj odd = v of the same d-group:
//   s_j = sum_{ai,r} p2[h, n]*acc[ai][2j][r]*acc[ai][2j+1][r]  (n lane-local)
// then shfl over qg, 1KB LDS combine over wm.  No 128 KB spill.
// ---------------------------------------------------------------------------
__global__ __launch_bounds__(512, 2) void kv_gemm_reduce(const bf16* __restrict__ A,
                                                         const bf16* __restrict__ B,
                                                         const float* __restrict__ p2,
                                                         float* __restrict__ partials) {
  __shared__ __align__(16) bf16 sh[65536];     // 128 KB staging
  __shared__ float red2[2][4][2][16];          // [wm][wn][j][l16]

  const int lin  = blockIdx.y * 6 + blockIdx.x;
  const int xcd  = lin & 7;
  const int j    = lin >> 3;                 // 0..95
  const int hh   = j % 6;
  const int mblk = xcd + 8 * (j / 6);        // 0..127, bijective
  const int m0   = mblk * 256;
  const int h0   = hh * 2;

  const int tid = threadIdx.x;
  const int tr  = tid >> 3;                                // 0..63
  const int tc  = ((tid & 7) ^ ((tid >> 3) & 7)) * 8;      // pre-swizzled col
  const bf16* pA = A + (size_t)(m0 + tr) * 768 + tc;
  // interleaved-kv B rows for slots r = tr, 64+tr, 128+tr, 192+tr
#define WQROW(r) (768 + (((r) >> 4) & 1) * 768 + (h0 + ((r) >> 7)) * 64 + \
                  ((((r) >> 5) & 3) * 16 + ((r) & 15)))
  const bf16* pB00 = B + (size_t)WQROW(tr) * 768 + tc;
  const bf16* pB01 = B + (size_t)WQROW(64 + tr) * 768 + tc;
  const bf16* pB10 = B + (size_t)WQROW(128 + tr) * 768 + tc;
  const bf16* pB11 = B + (size_t)WQROW(192 + tr) * 768 + tc;
#undef WQROW

  f32x4 acc[8][4] = {};
  gemm256(pA, pB00, pB01, pB10, pB11, sh, acc);

  // ---- in-register reduce: col c = wn*64 + bj*16 + l16 ->
  //      kv = bj&1, j2 = bj>>1, head = wn>>1, d = ((wn&1)*2 + j2)*16 + l16
  const int lane = tid & 63, wave = tid >> 6;
  const int wm = wave >> 2, wn = wave & 3, l16 = lane & 15, qg = lane >> 4;
  const float* p2h = p2 + (size_t)(h0 + (wn >> 1)) * 4096 + (m0 & 4095) + wm * 128;
  float s0 = 0.f, s1 = 0.f;
#pragma unroll
  for (int ai = 0; ai < 8; ++ai) {
    const float4 w = *(const float4*)(p2h + ai * 16 + qg * 4);  // broadcast
    s0 += w.x * acc[ai][0][0] * acc[ai][1][0] + w.y * acc[ai][0][1] * acc[ai][1][1]
        + w.z * acc[ai][0][2] * acc[ai][1][2] + w.w * acc[ai][0][3] * acc[ai][1][3];
    s1 += w.x * acc[ai][2][0] * acc[ai][3][0] + w.y * acc[ai][2][1] * acc[ai][3][1]
        + w.z * acc[ai][2][2] * acc[ai][3][2] + w.w * acc[ai][2][3] * acc[ai][3][3];
  }
  s0 += __shfl_xor(s0, 16); s0 += __shfl_xor(s0, 32);
  s1 += __shfl_xor(s1, 16); s1 += __shfl_xor(s1, 32);
  if (qg == 0) { red2[wm][wn][0][l16] = s0; red2[wm][wn][1][l16] = s1; }
  __syncthreads();
  if (tid < 128) {
    const int l = tid & 15, jj = (tid >> 4) & 1, wnn = tid >> 5;
    const float v = red2[0][wnn][jj][l] + red2[1][wnn][jj][l];
    const int hx = h0 + (wnn >> 1);
    const int dd = ((wnn & 1) * 2 + jj) * 16 + l;
    partials[((size_t)mblk * 12 + hx) * 64 + dd] = v;
  }
}

// ---------------------------------------------------------------------------
// Stage 2: sum the 16 per-mblk partials of each batch, then LayerNorm over d.
// grid (12 h, 8 b); 64 threads, d = lane.
// ---------------------------------------------------------------------------
__global__ __launch_bounds__(64) void mod_reduce_ln(const float* __restrict__ partials,
                                                    const float* __restrict__ gamma,
                                                    const float* __restrict__ beta,
                                                    float* __restrict__ mod) {
  const int h = blockIdx.x, b = blockIdx.y;
  const int d = threadIdx.x;

  const float* p = partials + ((size_t)(b * 16) * 12 + h) * 64 + d;
  float s = 0.f;
#pragma unroll
  for (int mb = 0; mb < 16; ++mb) s += p[(size_t)mb * 12 * 64];

  float sum = s, sumsq = s * s;
#pragma unroll
  for (int o = 32; o > 0; o >>= 1) {
    sum   += __shfl_xor(sum, o);
    sumsq += __shfl_xor(sumsq, o);
  }
  const float mu  = sum * (1.f / 64.f);
  const float var = sumsq * (1.f / 64.f) - mu * mu;
  const float r   = rsqrtf(var + LN_EPS);
  mod[(b * 12 + h) * 64 + d] = (s - mu) * r * gamma[d] + beta[d];
}

// ---------------------------------------------------------------------------
// Pass 2: q GEMM + fused modulation. Grid (3, 256) = 768 = 3 EXACT rounds
// (was 384 = 1.5 rounds).  128x256 tiles via core B.
// amod[m, c] = q[m, c] * p1[h(c), n(m)] * mod[b(m), c]  (bf16 out)
// ---------------------------------------------------------------------------
__global__ __launch_bounds__(512, 2) void q_gemm_mod(const bf16* __restrict__ A,
                                                     const bf16* __restrict__ B,
                                                     const float* __restrict__ p1,
                                                     const float* __restrict__ mod,
                                                     bf16* __restrict__ amod) {
  __shared__ __align__(16) bf16 sh[49152];   // 96 KB

  const int lin  = blockIdx.y * 3 + blockIdx.x;
  const int xcd  = lin & 7;
  const int j    = lin >> 3;                 // 0..95
  const int nblk = j % 3;
  const int mblk = xcd + 8 * (j / 3);        // 0..255
  const int n0   = nblk * 256;
  const int m0   = mblk * 128;

  const int tid = threadIdx.x;
  const int tr  = tid >> 3;
  const int tc  = ((tid & 7) ^ ((tid >> 3) & 7)) * 8;
  const bf16* qA   = A + (size_t)(m0 + tr) * 768 + tc;
  const bf16* qB00 = B + (size_t)(n0 + tr) * 768 + tc;
  const bf16* qB01 = qB00 + (size_t)64 * 768;
  const bf16* qB10 = qB00 + (size_t)128 * 768;
  const bf16* qB11 = qB00 + (size_t)192 * 768;

  f32x4 acc[4][4] = {};
  gemm128x256(qA, qB00, qB01, qB10, qB11, sh, acc);

  const int lane = tid & 63, wave = tid >> 6;
  const int wm = wave >> 2, wn = wave & 3, l16 = lane & 15, qg = lane >> 4;
  const int row0 = m0 + wm * 64 + qg * 4;
  const int col0 = n0 + wn * 64 + l16;
  const int b    = m0 >> 12;
  const int h    = (n0 >> 6) + wn;             // wave-uniform head

  float p1v[4][4];
#pragma unroll
  for (int ai = 0; ai < 4; ++ai)
#pragma unroll
    for (int r = 0; r < 4; ++r)
      p1v[ai][r] = p1[(size_t)h * 4096 + ((row0 + ai * 16 + r) & 4095)];
  float mv[4];
#pragma unroll
  for (int bj = 0; bj < 4; ++bj) mv[bj] = mod[b * 768 + col0 + bj * 16];

#pragma unroll
  for (int ai = 0; ai < 4; ++ai)
#pragma unroll
    for (int bj = 0; bj < 4; ++bj)
#pragma unroll
      for (int r = 0; r < 4; ++r)
        amod[(size_t)(row0 + ai * 16 + r) * 768 + col0 + bj * 16] =
            (bf16)(acc[ai][bj][r] * p1v[ai][r] * mv[bj]);
}

// ---------------------------------------------------------------------------
// Pass 3: out fp32 = amod @ w_proj^T + b_proj. Grid (3, 256) = 768 = 3 rounds.
// ---------------------------------------------------------------------------
__global__ __launch_bounds__(512, 2) void gemm_proj(const bf16* __restrict__ A,
                                                    const bf16* __restrict__ B,
                                                    const float* __restrict__ bias,
                                                    float* __restrict__ C) {
  __shared__ __align__(16) bf16 sh[49152];

  const int lin  = blockIdx.y * 3 + blockIdx.x;
  const int xcd  = lin & 7;
  const int j    = lin >> 3;
  const int nblk = j % 3;
  const int mblk = xcd + 8 * (j / 3);
  const int n0   = nblk * 256;
  const int m0   = mblk * 128;

  const int tid = threadIdx.x;
  const int tr  = tid >> 3;
  const int tc  = ((tid & 7) ^ ((tid >> 3) & 7)) * 8;
  const bf16* qA   = A + (size_t)(m0 + tr) * 768 + tc;
  const bf16* qB00 = B + (size_t)(n0 + tr) * 768 + tc;
  const bf16* qB01 = qB00 + (size_t)64 * 768;
  const bf16* qB10 = qB00 + (size_t)128 * 768;
  const bf16* qB11 = qB00 + (size_t)192 * 768;

  f32x4 acc[4][4] = {};
  gemm128x256(qA, qB00, qB01, qB10, qB11, sh, acc);

  const int lane = tid & 63, wave = tid >> 6;
  const int wm = wave >> 2, wn = wave & 3, l16 = lane & 15, qg = lane >> 4;
  const int row0 = m0 + wm * 64 + qg * 4;
  const int col0 = n0 + wn * 64 + l16;
#pragma unroll
  for (int bj = 0; bj < 4; ++bj) {
    const int col = col0 + bj * 16;
    const float bv = bias[col];
#pragma unroll
    for (int ai = 0; ai < 4; ++ai)
#pragma unroll
      for (int r = 0; r < 4; ++r)
        C[(size_t)(row0 + ai * 16 + r) * 768 + col] = acc[ai][bj][r] + bv;
  }
}

// ---------------------------------------------------------------------------
extern "C" void kernel_launch(void* const* d_in, const int* in_sizes, int n_in,
                              void* d_out, int out_size, void* d_ws, size_t ws_size,
                              hipStream_t stream) {
  (void)in_sizes; (void)n_in; (void)out_size; (void)ws_size;

  const float* x      = (const float*)d_in[0];   // [8,4096,768]
  const float* w_qkv  = (const float*)d_in[1];   // [2304,768]
  const float* w_proj = (const float*)d_in[2];   // [768,768]
  const float* b_proj = (const float*)d_in[3];   // [768]
  const float* p1     = (const float*)d_in[4];   // [12,4096]
  const float* p2     = (const float*)d_in[5];   // [12,4096]
  const float* gamma  = (const float*)d_in[6];   // [64]
  const float* beta   = (const float*)d_in[7];   // [64]
  float* out = (float*)d_out;                    // [8,4096,768] fp32

  char* ws = (char*)d_ws;
  bf16*  xb       = (bf16*)(ws + 0);              // 50,331,648  x bf16 [32768,768]
  bf16*  wqb      = (bf16*)(ws + 50331648);       //  3,538,944  w_qkv bf16
  bf16*  wpb      = (bf16*)(ws + 53870592);       //  1,179,648  w_proj bf16
  bf16*  amod     = (bf16*)(ws + 55050240);       // 50,331,648  amod bf16 [32768,768]
  float* partials = (float*)(ws + 105381888);     //    393,216  [128][12][64] f32
  float* mod      = (float*)(ws + 106168320);     //     24,576  [8][12][64] f32

  // 1) all fp32 -> bf16 conversions in one launch (26,880 blocks exact)
  cvt_all<<<26880, 256, 0, stream>>>(x, w_qkv, w_proj, xb, wqb, wpb);

  // 2) k/v GEMM + fused p2*k*v reduction (k,v never written to HBM)
  kv_gemm_reduce<<<dim3(6, 128), 512, 0, stream>>>(xb, wqb, p2, partials);

  // 3) finish reduction + LayerNorm -> mod [8,12,64]
  mod_reduce_ln<<<dim3(12, 8), 64, 0, stream>>>(partials, gamma, beta, mod);

  // 4) q GEMM + fused p1/mod modulation -> amod bf16 (3 exact rounds)
  q_gemm_mod<<<dim3(3, 256), 512, 0, stream>>>(xb, wqb, p1, mod, amod);

  // 5) proj GEMM + bias -> out fp32 (3 exact rounds)
  gemm_proj<<<dim3(3, 256), 512, 0, stream>>>(amod, wpb, b_proj, out);
}